// Round 1
// baseline (633.418 us; speedup 1.0000x reference)
//
#include <hip/hip_runtime.h>
#include <math.h>
#include <string.h>
#include <stdlib.h>

// ---------------- problem constants ----------------
#define F 32
#define M_TOT 9
#define NRBF 20
#define MAXNZ 256
#define PI_F 3.14159265358979323846f

// Compact CG nonzero list, grouped (sorted) by output index o.
struct CgArg {
    int off[10];                 // group boundaries per o: entries off[o]..off[o+1]
    unsigned char a[MAXNZ];      // input-1 index (0..8)
    unsigned char b[MAXNZ];      // Y index (0..8)
    unsigned char lb[MAXNZ];     // l of b (0..2) -> filter row
    float v[MAXNZ];              // CG value
};

// ---------------- host-side CG construction ----------------
static double factd(int n) {
    static const double f[9] = {1, 1, 2, 6, 24, 120, 720, 5040, 40320};
    return f[n];
}

static double cg_c(int j1, int m1, int j2, int m2, int j3, int m3) {
    if (m1 + m2 != m3) return 0.0;
    if (j3 < abs(j1 - j2) || j3 > j1 + j2) return 0.0;
    double pre = sqrt((2.0 * j3 + 1) * factd(j1 + j2 - j3) * factd(j1 - j2 + j3) *
                      factd(-j1 + j2 + j3) / factd(j1 + j2 + j3 + 1));
    pre *= sqrt(factd(j3 + m3) * factd(j3 - m3) * factd(j1 - m1) * factd(j1 + m1) *
                factd(j2 - m2) * factd(j2 + m2));
    double s = 0.0;
    for (int k = 0; k <= j1 + j2 + j3; k++) {
        int dd[6] = {k, j1 + j2 - j3 - k, j1 - m1 - k, j2 + m2 - k,
                     j3 - j2 + m1 + k, j3 - j1 - m2 + k};
        bool ok = true;
        for (int q = 0; q < 6; q++) if (dd[q] < 0) ok = false;
        if (!ok) continue;
        double t = 1.0;
        for (int q = 0; q < 6; q++) t *= factd(dd[q]);
        s += ((k & 1) ? -1.0 : 1.0) / t;
    }
    return pre * s;
}

static void u_real(int l, double Ur[5][5], double Ui[5][5]) {
    for (int i = 0; i < 5; i++)
        for (int j = 0; j < 5; j++) { Ur[i][j] = 0.0; Ui[i][j] = 0.0; }
    Ur[l][l] = 1.0;
    double s2 = 1.0 / sqrt(2.0);
    for (int m = 1; m <= l; m++) {
        double sgn = (m & 1) ? -1.0 : 1.0;
        Ur[l + m][l + m] = sgn * s2;   // (-1)^m / sqrt2
        Ur[l + m][l - m] = s2;         // 1/sqrt2
        Ui[l - m][l - m] = s2;         // i/sqrt2
        Ui[l - m][l + m] = -sgn * s2;  // -i(-1)^m/sqrt2
    }
}

static void build_cg(CgArg* out) {
    double CGD[9][9][9];
    memset(CGD, 0, sizeof(CGD));
    for (int l1 = 0; l1 <= 2; l1++)
        for (int l2 = 0; l2 <= 2; l2++)
            for (int l3 = 0; l3 <= 2; l3++) {
                if (l3 < abs(l1 - l2) || l3 > l1 + l2) continue;
                double U1r[5][5], U1i[5][5], U2r[5][5], U2i[5][5], U3r[5][5], U3i[5][5];
                u_real(l1, U1r, U1i);
                u_real(l2, U2r, U2i);
                u_real(l3, U3r, U3i);
                int n1 = 2 * l1 + 1, n2 = 2 * l2 + 1, n3 = 2 * l3 + 1;
                for (int aa = 0; aa < n1; aa++)
                    for (int bb = 0; bb < n2; bb++)
                        for (int cc = 0; cc < n3; cc++) {
                            double sr = 0.0;
                            for (int i = 0; i < n1; i++)
                                for (int j = 0; j < n2; j++)
                                    for (int k = 0; k < n3; k++) {
                                        double C = cg_c(l1, i - l1, l2, j - l2, l3, k - l3);
                                        if (C == 0.0) continue;
                                        double xr = U1r[aa][i], xi = U1i[aa][i];
                                        double yr = U2r[bb][j], yi = U2i[bb][j];
                                        double tr = xr * yr - xi * yi;
                                        double ti = xr * yi + xi * yr;
                                        double zr = U3r[cc][k], zi = -U3i[cc][k]; // conj
                                        sr += (tr * zr - ti * zi) * C;
                                    }
                            CGD[l1 * l1 + aa][l2 * l2 + bb][l3 * l3 + cc] = sr;
                        }
            }
    // extract nonzeros grouped by output index o (sum order irrelevant)
    int cnt = 0;
    for (int o = 0; o < 9; o++) {
        out->off[o] = cnt;
        for (int aa = 0; aa < 9; aa++)
            for (int bb = 0; bb < 9; bb++) {
                double v = CGD[aa][bb][o];
                if (fabs(v) > 1e-10 && cnt < MAXNZ) {
                    out->a[cnt] = (unsigned char)aa;
                    out->b[cnt] = (unsigned char)bb;
                    out->lb[cnt] = (unsigned char)((bb == 0) ? 0 : ((bb < 4) ? 1 : 2));
                    out->v[cnt] = (float)v;
                    cnt++;
                }
            }
    }
    out->off[9] = cnt;
}

// ---------------- device kernels ----------------

// x[n][0][f] = emb[Z[n]][f]; other m zero. x lives in d_out.
__global__ void init_x_kernel(float* __restrict__ x, const int* __restrict__ Z,
                              const float* __restrict__ emb, int N) {
    int idx = blockIdx.x * blockDim.x + threadIdx.x;
    if (idx >= N * 288) return;
    int n = idx / 288, r = idx % 288;
    x[idx] = (r < F) ? emb[Z[n] * F + r] : 0.0f;
}

// per-edge: Y[9], radial[20], cutoff
__global__ void geom_kernel(const float* __restrict__ rij, float* __restrict__ Y,
                            float* __restrict__ rad, float* __restrict__ cutv, int E) {
    int e = blockIdx.x * blockDim.x + threadIdx.x;
    if (e >= E) return;
    float x = rij[e * 3 + 0], y = rij[e * 3 + 1], z = rij[e * 3 + 2];
    float d = sqrtf(x * x + y * y + z * z);
    float inv = 1.0f / d;
    x *= inv; y *= inv; z *= inv;
    const float c0 = 0.28209479177387814f, c1 = 0.4886025119029199f;
    const float c2 = 1.0925484305920792f, c20 = 0.31539156525252005f;
    const float c22 = 0.5462742152960396f;
    float* Ye = Y + (size_t)e * 9;
    Ye[0] = c0;
    Ye[1] = c1 * y;
    Ye[2] = c1 * z;
    Ye[3] = c1 * x;
    Ye[4] = c2 * x * y;
    Ye[5] = c2 * y * z;
    Ye[6] = c20 * (3.0f * z * z - 1.0f);
    Ye[7] = c2 * x * z;
    Ye[8] = c22 * (x * x - y * y);
    const float step = 5.0f / 19.0f;
    const float coeff = -0.5f / (step * step);
    float* re = rad + (size_t)e * NRBF;
    for (int r = 0; r < NRBF; r++) {
        float t = d - step * (float)r;
        re[r] = expf(coeff * t * t);
    }
    cutv[e] = (d < 5.0f) ? 0.5f * (cosf(d * PI_F / 5.0f) + 1.0f) : 0.0f;
}

// per-edge message + scatter. 32 lanes per edge (lane = feature), 8 edges/block.
__global__ __launch_bounds__(256) void edge_kernel(
    const float* __restrict__ x, float* __restrict__ dx,
    const float* __restrict__ Y, const float* __restrict__ rad,
    const float* __restrict__ cutv,
    const int* __restrict__ idx_i, const int* __restrict__ idx_j,
    const float* __restrict__ fw, const float* __restrict__ fb,
    CgArg cg, int E) {
    __shared__ float xj_s[8][9][F];
    __shared__ float W_s[8][3][F];
    __shared__ float Y_s[8][9];

    int le = threadIdx.x >> 5;
    int f = threadIdx.x & 31;
    int e = blockIdx.x * 8 + le;
    if (e >= E) return;   // no __syncthreads in this kernel: each edge touched only by its own half-wave

    int j = idx_j[e];
    #pragma unroll
    for (int m = 0; m < 9; m++)
        xj_s[le][m][f] = x[(size_t)j * 288 + m * F + f];

    if (f < 9) Y_s[le][f] = Y[(size_t)e * 9 + f];

    // W[lc][f] = (sum_r rad[r]*fw[r][lc*F+f] + fb[lc*F+f]) * cut
    float rr[NRBF];
    #pragma unroll
    for (int r = 0; r < NRBF; r++) rr[r] = rad[(size_t)e * NRBF + r];
    float cu = cutv[e];
    #pragma unroll
    for (int lc = 0; lc < 3; lc++) {
        float acc = fb[lc * F + f];
        #pragma unroll
        for (int r = 0; r < NRBF; r++)
            acc += rr[r] * fw[r * 96 + lc * F + f];
        W_s[le][lc][f] = acc * cu;
    }

    // CG contraction, accumulators kept in registers (o compile-time via unroll)
    float msg[9];
    #pragma unroll
    for (int o = 0; o < 9; o++) {
        float acc = 0.0f;
        for (int t = cg.off[o]; t < cg.off[o + 1]; t++) {
            float xv = xj_s[le][cg.a[t]][f];
            float yv = Y_s[le][cg.b[t]];
            float wv = W_s[le][cg.lb[t]][f];
            acc += xv * (yv * cg.v[t]) * wv;
        }
        msg[o] = acc;
    }

    int i = idx_i[e];
    #pragma unroll
    for (int o = 0; o < 9; o++)
        atomicAdd(&dx[(size_t)i * 288 + o * F + f], msg[o]);
}

// per-node: mix1, CG self-product, mix2, gate, mix3, residual add. 8 nodes/block.
__global__ __launch_bounds__(256) void node_kernel(
    float* __restrict__ x, const float* __restrict__ dx,
    const float* __restrict__ m1w, const float* __restrict__ m2w,
    const float* __restrict__ m3w,
    const float* __restrict__ gw, const float* __restrict__ gb,
    CgArg cg, int N) {
    __shared__ float dx_s[8][9][F];
    __shared__ float t_s[8][9][F];
    __shared__ float sig_s[8][3][F];
    __shared__ float m1_s[F * F], m2_s[F * F], m3_s[F * F], gw_s[F * 96];

    for (int k = threadIdx.x; k < F * F; k += 256) {
        m1_s[k] = m1w[k];
        m2_s[k] = m2w[k];
        m3_s[k] = m3w[k];
    }
    for (int k = threadIdx.x; k < F * 96; k += 256) gw_s[k] = gw[k];
    __syncthreads();

    int ln = threadIdx.x >> 5;
    int f = threadIdx.x & 31;
    int n = blockIdx.x * 8 + ln;
    if (n >= N) return;

    #pragma unroll
    for (int m = 0; m < 9; m++)
        dx_s[ln][m][f] = dx[(size_t)n * 288 + m * F + f];

    // ddx = dx @ mix1 -> t_s
    #pragma unroll
    for (int m = 0; m < 9; m++) {
        float acc = 0.0f;
        for (int g = 0; g < F; g++)
            acc += dx_s[ln][m][g] * m1_s[g * F + f];
        t_s[ln][m][f] = acc;
    }

    // p[o] = sum_t dx[a]*ddx[b]*v
    float p[9];
    #pragma unroll
    for (int o = 0; o < 9; o++) {
        float acc = 0.0f;
        for (int t = cg.off[o]; t < cg.off[o + 1]; t++)
            acc += dx_s[ln][cg.a[t]][f] * t_s[ln][cg.b[t]][f] * cg.v[t];
        p[o] = acc;
    }
    // dx + p -> t_s
    #pragma unroll
    for (int m = 0; m < 9; m++)
        t_s[ln][m][f] = dx_s[ln][m][f] + p[m];

    // dx2 = (dx+p) @ mix2 -> dx_s
    #pragma unroll
    for (int m = 0; m < 9; m++) {
        float acc = 0.0f;
        for (int g = 0; g < F; g++)
            acc += t_s[ln][m][g] * m2_s[g * F + f];
        dx_s[ln][m][f] = acc;
    }

    // gate from dx2[:,0]
    #pragma unroll
    for (int lc = 0; lc < 3; lc++) {
        float acc = gb[lc * F + f];
        for (int g = 0; g < F; g++)
            acc += dx_s[ln][0][g] * gw_s[g * 96 + lc * F + f];
        sig_s[ln][lc][f] = 1.0f / (1.0f + expf(-acc));
    }

    // gated -> t_s
    const int lidx[9] = {0, 1, 1, 1, 2, 2, 2, 2, 2};
    #pragma unroll
    for (int m = 0; m < 9; m++)
        t_s[ln][m][f] = dx_s[ln][m][f] * sig_s[ln][lidx[m]][f];

    // out = gated @ mix3; x += out
    #pragma unroll
    for (int m = 0; m < 9; m++) {
        float acc = 0.0f;
        for (int g = 0; g < F; g++)
            acc += t_s[ln][m][g] * m3_s[g * F + f];
        x[(size_t)n * 288 + m * F + f] += acc;
    }
}

// ---------------- launch ----------------
extern "C" void kernel_launch(void* const* d_in, const int* in_sizes, int n_in,
                              void* d_out, int out_size, void* d_ws, size_t ws_size,
                              hipStream_t stream) {
    int N = in_sizes[0];
    int E = in_sizes[2];
    int L = in_sizes[5] / (NRBF * 3 * F);   // layers

    const int* Z = (const int*)d_in[0];
    const float* rij = (const float*)d_in[1];
    const int* idx_i = (const int*)d_in[2];
    const int* idx_j = (const int*)d_in[3];
    const float* emb = (const float*)d_in[4];
    const float* filt_w = (const float*)d_in[5];
    const float* filt_b = (const float*)d_in[6];
    const float* m1w = (const float*)d_in[7];
    const float* m2w = (const float*)d_in[8];
    const float* m3w = (const float*)d_in[9];
    const float* gw = (const float*)d_in[10];
    const float* gb = (const float*)d_in[11];
    float* x = (float*)d_out;   // x buffer lives in d_out

    float* ws = (float*)d_ws;
    float* Yb = ws;                        // E*9
    float* radb = Yb + (size_t)E * 9;      // E*20
    float* cutb = radb + (size_t)E * NRBF; // E
    float* dxb = cutb + E;                 // N*288

    CgArg cg;
    build_cg(&cg);

    init_x_kernel<<<(N * 288 + 255) / 256, 256, 0, stream>>>(x, Z, emb, N);
    geom_kernel<<<(E + 255) / 256, 256, 0, stream>>>(rij, Yb, radb, cutb, E);

    for (int li = 0; li < L; li++) {
        hipMemsetAsync(dxb, 0, (size_t)N * 288 * sizeof(float), stream);
        edge_kernel<<<(E + 7) / 8, 256, 0, stream>>>(
            x, dxb, Yb, radb, cutb, idx_i, idx_j,
            filt_w + (size_t)li * NRBF * 96, filt_b + (size_t)li * 96, cg, E);
        node_kernel<<<(N + 7) / 8, 256, 0, stream>>>(
            x, dxb, m1w + (size_t)li * F * F, m2w + (size_t)li * F * F,
            m3w + (size_t)li * F * F, gw + (size_t)li * F * 96,
            gb + (size_t)li * 96, cg, N);
    }
}

// Round 2
// 272.644 us; speedup vs baseline: 2.3232x; 2.3232x over previous
//
#include <hip/hip_runtime.h>
#include <math.h>

// ---------------- problem constants ----------------
#define F 32
#define NRBF 20
#define MAXNZ 192
#define PI_F 3.14159265358979323846f

// ---------------- compile-time CG construction ----------------
struct CgCE {
    int cnt;
    int off[10];
    int a[MAXNZ];
    int b[MAXNZ];
    int lb[MAXNZ];
    float v[MAXNZ];
};

constexpr double cfact(int n) { double r = 1.0; for (int i = 2; i <= n; i++) r *= (double)i; return r; }
constexpr double csqrt(double x) {
    if (x <= 0.0) return 0.0;
    double r = x < 1.0 ? 1.0 : x;
    for (int i = 0; i < 80; i++) r = 0.5 * (r + x / r);
    return r;
}
constexpr int cabs_i(int x) { return x < 0 ? -x : x; }

constexpr double cg_c(int j1, int m1, int j2, int m2, int j3, int m3) {
    if (m1 + m2 != m3) return 0.0;
    if (j3 < cabs_i(j1 - j2) || j3 > j1 + j2) return 0.0;
    double pre = csqrt((2.0 * j3 + 1) * cfact(j1 + j2 - j3) * cfact(j1 - j2 + j3) *
                       cfact(-j1 + j2 + j3) / cfact(j1 + j2 + j3 + 1));
    pre *= csqrt(cfact(j3 + m3) * cfact(j3 - m3) * cfact(j1 - m1) * cfact(j1 + m1) *
                 cfact(j2 - m2) * cfact(j2 + m2));
    double s = 0.0;
    for (int k = 0; k <= j1 + j2 + j3; k++) {
        int d0 = k, d1 = j1 + j2 - j3 - k, d2 = j1 - m1 - k, d3 = j2 + m2 - k;
        int d4 = j3 - j2 + m1 + k, d5 = j3 - j1 - m2 + k;
        if (d0 < 0 || d1 < 0 || d2 < 0 || d3 < 0 || d4 < 0 || d5 < 0) continue;
        double t = cfact(d0) * cfact(d1) * cfact(d2) * cfact(d3) * cfact(d4) * cfact(d5);
        s += ((k & 1) ? -1.0 : 1.0) / t;
    }
    return pre * s;
}

struct U5 { double re[5][5]; double im[5][5]; };
constexpr U5 u_real(int l) {
    U5 u{};
    u.re[l][l] = 1.0;
    double s2 = 1.0 / csqrt(2.0);
    for (int m = 1; m <= l; m++) {
        double sgn = (m & 1) ? -1.0 : 1.0;
        u.re[l + m][l + m] = sgn * s2;
        u.re[l + m][l - m] = s2;
        u.im[l - m][l - m] = s2;
        u.im[l - m][l + m] = -sgn * s2;
    }
    return u;
}

struct Dense { double c[9][9][9]; };
constexpr Dense build_dense() {
    Dense D{};
    for (int l1 = 0; l1 <= 2; l1++)
        for (int l2 = 0; l2 <= 2; l2++)
            for (int l3 = 0; l3 <= 2; l3++) {
                if (l3 < cabs_i(l1 - l2) || l3 > l1 + l2) continue;
                U5 U1 = u_real(l1), U2 = u_real(l2), U3 = u_real(l3);
                int n1 = 2 * l1 + 1, n2 = 2 * l2 + 1, n3 = 2 * l3 + 1;
                for (int i = 0; i < n1; i++)
                    for (int j = 0; j < n2; j++) {
                        int k = (i - l1) + (j - l2) + l3;   // m3 = m1+m2
                        if (k < 0 || k >= n3) continue;
                        double C = cg_c(l1, i - l1, l2, j - l2, l3, k - l3);
                        if (C == 0.0) continue;
                        // U columns i/j/k have nonzeros only at rows {i, n-1-i} etc.
                        int as[2] = {i, n1 - 1 - i}, bs[2] = {j, n2 - 1 - j}, cs[2] = {k, n3 - 1 - k};
                        int na = (as[0] == as[1]) ? 1 : 2;
                        int nb = (bs[0] == bs[1]) ? 1 : 2;
                        int nc = (cs[0] == cs[1]) ? 1 : 2;
                        for (int ai = 0; ai < na; ai++)
                            for (int bi = 0; bi < nb; bi++)
                                for (int ci = 0; ci < nc; ci++) {
                                    int aa = as[ai], bb = bs[bi], cc = cs[ci];
                                    double xr = U1.re[aa][i], xi = U1.im[aa][i];
                                    double yr = U2.re[bb][j], yi = U2.im[bb][j];
                                    double tr = xr * yr - xi * yi;
                                    double ti = xr * yi + xi * yr;
                                    double zr = U3.re[cc][k], zi = -U3.im[cc][k]; // conj
                                    double add = (tr * zr - ti * zi) * C;
                                    if (add != 0.0)
                                        D.c[l1 * l1 + aa][l2 * l2 + bb][l3 * l3 + cc] += add;
                                }
                    }
            }
    return D;
}

constexpr CgCE build_cg() {
    CgCE t{};
    Dense D = build_dense();
    int cnt = 0;
    for (int o = 0; o < 9; o++) {
        t.off[o] = cnt;
        for (int aa = 0; aa < 9; aa++)
            for (int bb = 0; bb < 9; bb++) {
                double v = D.c[aa][bb][o];
                if (v > 1e-10 || v < -1e-10) {
                    t.a[cnt] = aa;
                    t.b[cnt] = bb;
                    t.lb[cnt] = (bb == 0) ? 0 : ((bb < 4) ? 1 : 2);
                    t.v[cnt] = (float)v;
                    cnt++;
                }
            }
    }
    t.off[9] = cnt;
    t.cnt = cnt;
    return t;
}

constexpr CgCE CG = build_cg();
static_assert(CG.cnt <= MAXNZ, "CG nnz overflow");
static_assert(CG.cnt > 0, "CG empty");

// ---------------- device kernels ----------------

__global__ void init_x_kernel(float* __restrict__ x, const int* __restrict__ Z,
                              const float* __restrict__ emb, int N) {
    int idx = blockIdx.x * blockDim.x + threadIdx.x;
    if (idx >= N * 288) return;
    int n = idx / 288, r = idx % 288;
    x[idx] = (r < F) ? emb[Z[n] * F + r] : 0.0f;
}

// per-edge: radial[20], cutoff
__global__ void geom_kernel(const float* __restrict__ rij,
                            float* __restrict__ rad, float* __restrict__ cutv, int E) {
    int e = blockIdx.x * blockDim.x + threadIdx.x;
    if (e >= E) return;
    float x = rij[e * 3 + 0], y = rij[e * 3 + 1], z = rij[e * 3 + 2];
    float d = sqrtf(x * x + y * y + z * z);
    const float step = 5.0f / 19.0f;
    const float coeff = -0.5f / (step * step);
    float* re = rad + (size_t)e * NRBF;
    #pragma unroll
    for (int r = 0; r < NRBF; r++) {
        float t = d - step * (float)r;
        re[r] = expf(coeff * t * t);
    }
    cutv[e] = (d < 5.0f) ? 0.5f * (cosf(d * PI_F / 5.0f) + 1.0f) : 0.0f;
}

// per-edge message + scatter. 32 lanes/edge, 8 edges/block. LDS-free, register CG.
__global__ __launch_bounds__(256, 4) void edge_kernel(
    const float* __restrict__ x, float* __restrict__ dx,
    const float* __restrict__ rij, const float* __restrict__ rad,
    const float* __restrict__ cutv,
    const int* __restrict__ idx_i, const int* __restrict__ idx_j,
    const float* __restrict__ fw, const float* __restrict__ fb, int E) {
    int f = threadIdx.x & 31;
    int le = threadIdx.x >> 5;
    int e = blockIdx.x * 8 + le;

    // filter weights per-lane in VGPRs (L1-hot; same for every edge)
    float frw[NRBF * 3];
    #pragma unroll
    for (int r = 0; r < NRBF; r++)
        #pragma unroll
        for (int lc = 0; lc < 3; lc++)
            frw[r * 3 + lc] = fw[r * 96 + lc * F + f];
    float b0 = fb[f], b1 = fb[F + f], b2 = fb[2 * F + f];

    if (e >= E) return;

    // W filter: rad broadcast loads, MAC into 3 accumulators
    const float* re = rad + (size_t)e * NRBF;
    float W0 = b0, W1 = b1, W2 = b2;
    #pragma unroll
    for (int r = 0; r < NRBF; r++) {
        float rv = re[r];
        W0 += rv * frw[r * 3 + 0];
        W1 += rv * frw[r * 3 + 1];
        W2 += rv * frw[r * 3 + 2];
    }
    float cu = cutv[e];
    W0 *= cu; W1 *= cu; W2 *= cu;

    // Y recomputed from rij (broadcast loads)
    float rx = rij[3 * e + 0], ry = rij[3 * e + 1], rz = rij[3 * e + 2];
    float dd = sqrtf(rx * rx + ry * ry + rz * rz);
    float inv = 1.0f / dd;
    rx *= inv; ry *= inv; rz *= inv;
    const float c0 = 0.28209479177387814f, c1 = 0.4886025119029199f;
    const float c2 = 1.0925484305920792f, c20 = 0.31539156525252005f;
    const float c22 = 0.5462742152960396f;
    float Yv[9];
    Yv[0] = c0;
    Yv[1] = c1 * ry;
    Yv[2] = c1 * rz;
    Yv[3] = c1 * rx;
    Yv[4] = c2 * rx * ry;
    Yv[5] = c2 * ry * rz;
    Yv[6] = c20 * (3.0f * rz * rz - 1.0f);
    Yv[7] = c2 * rx * rz;
    Yv[8] = c22 * (rx * rx - ry * ry);

    // gather x[j]
    int j = idx_j[e];
    const float* xj_p = x + (size_t)j * 288;
    float xj[9];
    #pragma unroll
    for (int m = 0; m < 9; m++) xj[m] = xj_p[m * F + f];

    // register CG contraction (all indices compile-time)
    float msg[9];
    #pragma unroll
    for (int o = 0; o < 9; o++) {
        float acc = 0.0f;
        #pragma unroll
        for (int t = CG.off[o]; t < CG.off[o + 1]; t++) {
            float w = (CG.lb[t] == 0) ? W0 : ((CG.lb[t] == 1) ? W1 : W2);
            acc += xj[CG.a[t]] * (Yv[CG.b[t]] * CG.v[t]) * w;
        }
        msg[o] = acc;
    }

    int i = idx_i[e];
    float* dp = dx + (size_t)i * 288;
    #pragma unroll
    for (int o = 0; o < 9; o++)
        atomicAdd(&dp[o * F + f], msg[o]);
}

// per-node: mix1, CG self-product, mix2, gate, mix3, residual. 8 nodes/block.
// Weights in VGPRs, dx broadcasts via ds_read_b128, CG fully in registers.
__global__ __launch_bounds__(256, 4) void node_kernel(
    float* __restrict__ x, const float* __restrict__ dxg,
    const float* __restrict__ m1w, const float* __restrict__ m2w,
    const float* __restrict__ m3w,
    const float* __restrict__ gw, const float* __restrict__ gbias, int N) {
    __shared__ float bc_s[8][9][F];     // broadcast buffer, reused per phase
    __shared__ float gw_s[F * 96];      // gate weights

    for (int k = threadIdx.x; k < F * 96; k += 256) gw_s[k] = gw[k];
    __syncthreads();

    int ln = threadIdx.x >> 5, f = threadIdx.x & 31;
    int n = blockIdx.x * 8 + ln;
    if (n >= N) return;

    const float* dxp = dxg + (size_t)n * 288;
    float dxr[9];
    #pragma unroll
    for (int m = 0; m < 9; m++) {
        dxr[m] = dxp[m * F + f];
        bc_s[ln][m][f] = dxr[m];     // same-wave write->read, no barrier needed
    }

    float wreg[F];
    #pragma unroll
    for (int g = 0; g < F; g++) wreg[g] = m1w[g * F + f];

    // ddx = dx @ mix1   (broadcast b128 reads of dx, weights in regs)
    float ddx[9];
    #pragma unroll
    for (int m = 0; m < 9; m++) {
        float acc = 0.0f;
        #pragma unroll
        for (int gb = 0; gb < 8; gb++) {
            float4 dv = *(const float4*)&bc_s[ln][m][gb * 4];
            acc += dv.x * wreg[gb * 4 + 0];
            acc += dv.y * wreg[gb * 4 + 1];
            acc += dv.z * wreg[gb * 4 + 2];
            acc += dv.w * wreg[gb * 4 + 3];
        }
        ddx[m] = acc;
    }

    // p = CG(dx, ddx) entirely in registers; tr = dx + p
    float tr[9];
    #pragma unroll
    for (int o = 0; o < 9; o++) {
        float acc = 0.0f;
        #pragma unroll
        for (int t = CG.off[o]; t < CG.off[o + 1]; t++)
            acc += dxr[CG.a[t]] * ddx[CG.b[t]] * CG.v[t];
        tr[o] = dxr[o] + acc;
    }

    // stage tr for broadcast, mix2
    #pragma unroll
    for (int m = 0; m < 9; m++) bc_s[ln][m][f] = tr[m];
    #pragma unroll
    for (int g = 0; g < F; g++) wreg[g] = m2w[g * F + f];
    float dx2[9];
    #pragma unroll
    for (int m = 0; m < 9; m++) {
        float acc = 0.0f;
        #pragma unroll
        for (int gb = 0; gb < 8; gb++) {
            float4 dv = *(const float4*)&bc_s[ln][m][gb * 4];
            acc += dv.x * wreg[gb * 4 + 0];
            acc += dv.y * wreg[gb * 4 + 1];
            acc += dv.z * wreg[gb * 4 + 2];
            acc += dv.w * wreg[gb * 4 + 3];
        }
        dx2[m] = acc;
    }

    // gate from dx2[:,0]
    bc_s[ln][0][f] = dx2[0];
    float ga0 = gbias[f], ga1 = gbias[F + f], ga2 = gbias[2 * F + f];
    #pragma unroll
    for (int gb = 0; gb < 8; gb++) {
        float4 dv = *(const float4*)&bc_s[ln][0][gb * 4];
        float dj[4] = {dv.x, dv.y, dv.z, dv.w};
        #pragma unroll
        for (int jj = 0; jj < 4; jj++) {
            int g = gb * 4 + jj;
            ga0 += dj[jj] * gw_s[g * 96 + 0 * F + f];
            ga1 += dj[jj] * gw_s[g * 96 + 1 * F + f];
            ga2 += dj[jj] * gw_s[g * 96 + 2 * F + f];
        }
    }
    float s0 = 1.0f / (1.0f + expf(-ga0));
    float s1 = 1.0f / (1.0f + expf(-ga1));
    float s2 = 1.0f / (1.0f + expf(-ga2));

    // gated
    float gt[9];
    gt[0] = dx2[0] * s0;
    gt[1] = dx2[1] * s1; gt[2] = dx2[2] * s1; gt[3] = dx2[3] * s1;
    gt[4] = dx2[4] * s2; gt[5] = dx2[5] * s2; gt[6] = dx2[6] * s2;
    gt[7] = dx2[7] * s2; gt[8] = dx2[8] * s2;

    // stage gated, mix3, residual add into x
    #pragma unroll
    for (int m = 0; m < 9; m++) bc_s[ln][m][f] = gt[m];
    #pragma unroll
    for (int g = 0; g < F; g++) wreg[g] = m3w[g * F + f];
    float* xp = x + (size_t)n * 288;
    #pragma unroll
    for (int m = 0; m < 9; m++) {
        float acc = 0.0f;
        #pragma unroll
        for (int gb = 0; gb < 8; gb++) {
            float4 dv = *(const float4*)&bc_s[ln][m][gb * 4];
            acc += dv.x * wreg[gb * 4 + 0];
            acc += dv.y * wreg[gb * 4 + 1];
            acc += dv.z * wreg[gb * 4 + 2];
            acc += dv.w * wreg[gb * 4 + 3];
        }
        xp[m * F + f] += acc;
    }
}

// ---------------- launch ----------------
extern "C" void kernel_launch(void* const* d_in, const int* in_sizes, int n_in,
                              void* d_out, int out_size, void* d_ws, size_t ws_size,
                              hipStream_t stream) {
    int N = in_sizes[0];
    int E = in_sizes[2];
    int L = in_sizes[5] / (NRBF * 3 * F);   // layers

    const int* Z = (const int*)d_in[0];
    const float* rij = (const float*)d_in[1];
    const int* idx_i = (const int*)d_in[2];
    const int* idx_j = (const int*)d_in[3];
    const float* emb = (const float*)d_in[4];
    const float* filt_w = (const float*)d_in[5];
    const float* filt_b = (const float*)d_in[6];
    const float* m1w = (const float*)d_in[7];
    const float* m2w = (const float*)d_in[8];
    const float* m3w = (const float*)d_in[9];
    const float* gw = (const float*)d_in[10];
    const float* gb = (const float*)d_in[11];
    float* x = (float*)d_out;

    float* ws = (float*)d_ws;
    float* radb = ws;                       // E*20
    float* cutb = radb + (size_t)E * NRBF;  // E
    float* dxb = cutb + E;                  // N*288

    init_x_kernel<<<(N * 288 + 255) / 256, 256, 0, stream>>>(x, Z, emb, N);
    geom_kernel<<<(E + 255) / 256, 256, 0, stream>>>(rij, radb, cutb, E);

    for (int li = 0; li < L; li++) {
        hipMemsetAsync(dxb, 0, (size_t)N * 288 * sizeof(float), stream);
        edge_kernel<<<(E + 7) / 8, 256, 0, stream>>>(
            x, dxb, rij, radb, cutb, idx_i, idx_j,
            filt_w + (size_t)li * NRBF * 96, filt_b + (size_t)li * 96, E);
        node_kernel<<<(N + 7) / 8, 256, 0, stream>>>(
            x, dxb, m1w + (size_t)li * F * F, m2w + (size_t)li * F * F,
            m3w + (size_t)li * F * F, gw + (size_t)li * F * 96,
            gb + (size_t)li * 96, N);
    }
}